// Round 10
// baseline (9625.317 us; speedup 1.0000x reference)
//
#include <hip/hip_runtime.h>
#include <hip/hip_bf16.h>
#include <math.h>

#define NTOK 2304
#define CDIM 256
#define NH 4
#define DHD 64

typedef __hip_bfloat16 bf16;

// block-wide sum over 256 threads; all threads receive the result
__device__ __forceinline__ float blk_sum256(float v, float* red){
  int t = threadIdx.x;
  red[t] = v; __syncthreads();
  #pragma unroll
  for (int s = 128; s > 0; s >>= 1){
    if (t < s) red[t] += red[t+s];
    __syncthreads();
  }
  float r = red[0]; __syncthreads();
  return r;
}

__device__ __forceinline__ void fma4(const float4 w, const float* x, int c, float& acc){
  acc += w.x*x[c] + w.y*x[c+1] + w.z*x[c+2] + w.w*x[c+3];
}

// ---------------- K0: sentinel fill (f32) ----------------
__global__ __launch_bounds__(256) void k_fill(float* __restrict__ out, int n, float v){
  int i = blockIdx.x*256 + threadIdx.x;
  if (i < n) out[i] = v;
}

// ---------------- K1: sampling agent logits ----------------
__global__ __launch_bounds__(256) void k_agent(const float* __restrict__ fir, const float* __restrict__ fvis,
    const float* __restrict__ aw1, const float* __restrict__ ab1,
    const float* __restrict__ aw2, const float* __restrict__ ab2,
    float* __restrict__ lf)
{
  __shared__ float xv[512];
  __shared__ float red[256];
  int t = threadIdx.x;
  int pix = blockIdx.x;
  int b = pix / NTOK, n = pix % NTOK;
  xv[t]     = fir [(size_t)(b*CDIM + t)*NTOK + n];
  xv[t+256] = fvis[(size_t)(b*CDIM + t)*NTOK + n];
  __syncthreads();
  float part = 0.f;
  #pragma unroll
  for (int oi = 0; oi < 2; ++oi){
    int o = t + oi*256;
    const float4* w4 = reinterpret_cast<const float4*>(aw1 + (size_t)o*512);
    float acc = ab1[o];
    #pragma unroll 8
    for (int c4 = 0; c4 < 128; ++c4){
      fma4(w4[c4], xv, c4*4, acc);
    }
    float s = acc / (1.f + expf(-acc));   // SiLU
    part += s * aw2[o];
  }
  float tot = blk_sum256(part, red);
  if (t == 0) lf[pix] = tot + ab2[0];
}

// ---------------- K2: selection mask + top-64 fallback (OOB hardened) ----------------
__global__ __launch_bounds__(256) void k_select(const float* __restrict__ lf,
    float* __restrict__ msk, int* __restrict__ sel)
{
  __shared__ float vals[NTOK];
  __shared__ int   ired[256];
  __shared__ float rmax[256];
  __shared__ int   rix[256];
  int b = blockIdx.x;
  int t = threadIdx.x;
  int cnt = 0;
  for (int n = t; n < NTOK; n += 256){
    float v = lf[b*NTOK + n];
    vals[n] = v;
    int m = (v > 0.f) ? 1 : 0;
    msk[b*NTOK + n] = (float)m;
    sel[b*NTOK + n] = m;
    cnt += m;
  }
  ired[t] = cnt; __syncthreads();
  #pragma unroll
  for (int s = 128; s > 0; s >>= 1){
    if (t < s) ired[t] += ired[t+s];
    __syncthreads();
  }
  int count = ired[0];
  __syncthreads();
  if (count < 64){
    for (int n = t; n < NTOK; n += 256) sel[b*NTOK + n] = 0;
    __syncthreads();
    for (int it = 0; it < 64; ++it){
      float bestv = -INFINITY; int besti = t;   // hardened: always valid
      for (int n = t; n < NTOK; n += 256){
        float v = vals[n];
        if (v > bestv || (v == bestv && n < besti)){ bestv = v; besti = n; }
      }
      rmax[t] = bestv; rix[t] = besti; __syncthreads();
      #pragma unroll
      for (int s = 128; s > 0; s >>= 1){
        if (t < s){
          if (rmax[t+s] > rmax[t] || (rmax[t+s] == rmax[t] && rix[t+s] < rix[t])){
            rmax[t] = rmax[t+s]; rix[t] = rix[t+s];
          }
        }
        __syncthreads();
      }
      if (t == 0){
        int w = rix[0];
        if (w >= 0 && w < NTOK){ sel[b*NTOK + w] = 1; vals[w] = -INFINITY; }
      }
      __syncthreads();
    }
  }
}

// ---------------- K3: LN + QKV projection ----------------
__global__ __launch_bounds__(256) void k_ln_qkv(const float* __restrict__ f,
    const float* __restrict__ lng, const float* __restrict__ lnb,
    const float* __restrict__ wqkv, const float* __restrict__ bqkv,
    float* __restrict__ qkv)
{
  __shared__ float xn[256];
  __shared__ float red[256];
  int t = threadIdx.x;
  int pix = blockIdx.x;
  int b = pix / NTOK, n = pix % NTOK;
  float x = f[(size_t)(b*CDIM + t)*NTOK + n];
  float m  = blk_sum256(x,   red) * (1.f/256.f);
  float sq = blk_sum256(x*x, red) * (1.f/256.f);
  float rstd = rsqrtf(sq - m*m + 1e-5f);
  xn[t] = (x - m)*rstd*lng[t] + lnb[t];
  __syncthreads();
  size_t obase = (size_t)pix * 768;
  #pragma unroll
  for (int oi = 0; oi < 3; ++oi){
    int o = t + oi*256;
    const float4* w4 = reinterpret_cast<const float4*>(wqkv + (size_t)o*256);
    float acc = bqkv[o];
    #pragma unroll 8
    for (int c4 = 0; c4 < 64; ++c4){
      fma4(w4[c4], xn, c4*4, acc);
    }
    qkv[obase + o] = acc;
  }
}

// ---------------- K4: masked attention (online softmax, flash-style) ----------------
__global__ __launch_bounds__(256) void k_attn(const float* __restrict__ qkv,
    const int* __restrict__ sel, float* __restrict__ attno)
{
  __shared__ float qs[16*66];
  __shared__ float Ks[64*65];
  __shared__ float Vs[64*65];
  __shared__ float ps[16*68];
  __shared__ int selk[64];
  int t = threadIdx.x;
  int bi = blockIdx.x;
  int qt = bi % 144; int h = (bi/144) % NH; int b = bi / (144*NH);
  for (int idx = t; idx < 16*64; idx += 256){
    int r = idx >> 6, d = idx & 63;
    qs[r*66 + d] = qkv[(size_t)(b*NTOK + qt*16 + r)*768 + h*64 + d];
  }
  int r = t >> 4, c = t & 15;
  float m = -INFINITY, l = 0.f;
  float o0=0.f, o1=0.f, o2=0.f, o3=0.f;
  for (int kt = 0; kt < 36; ++kt){
    __syncthreads();   // previous-tile LDS reads done (also covers qs staging)
    for (int idx = t; idx < 64*64; idx += 256){
      int kr = idx >> 6, d = idx & 63;
      size_t base = (size_t)(b*NTOK + kt*64 + kr)*768 + h*64 + d;
      Ks[kr*65 + d] = qkv[base + 256];
      Vs[kr*65 + d] = qkv[base + 512];
    }
    if (t < 64) selk[t] = sel[b*NTOK + kt*64 + t];
    __syncthreads();
    float s0=0.f, s1=0.f, s2=0.f, s3=0.f;
    const float* qrow = qs + r*66;
    const float* k0 = Ks + (c*4+0)*65;
    const float* k1 = Ks + (c*4+1)*65;
    const float* k2 = Ks + (c*4+2)*65;
    const float* k3 = Ks + (c*4+3)*65;
    #pragma unroll 8
    for (int d = 0; d < 64; ++d){
      float qv = qrow[d];
      s0 += qv*k0[d]; s1 += qv*k1[d]; s2 += qv*k2[d]; s3 += qv*k3[d];
    }
    s0 *= 0.125f; s1 *= 0.125f; s2 *= 0.125f; s3 *= 0.125f;
    if (!selk[c*4+0]) s0 = -1e9f;
    if (!selk[c*4+1]) s1 = -1e9f;
    if (!selk[c*4+2]) s2 = -1e9f;
    if (!selk[c*4+3]) s3 = -1e9f;
    float smax = fmaxf(fmaxf(s0,s1), fmaxf(s2,s3));
    #pragma unroll
    for (int off = 8; off; off >>= 1) smax = fmaxf(smax, __shfl_xor(smax, off, 16));
    float mnew = fmaxf(m, smax);
    float fs = expf(m - mnew);
    float p0 = expf(s0 - mnew), p1 = expf(s1 - mnew), p2 = expf(s2 - mnew), p3 = expf(s3 - mnew);
    ps[r*68 + c*4 + 0] = p0; ps[r*68 + c*4 + 1] = p1;
    ps[r*68 + c*4 + 2] = p2; ps[r*68 + c*4 + 3] = p3;
    float psum = p0+p1+p2+p3;
    #pragma unroll
    for (int off = 8; off; off >>= 1) psum += __shfl_xor(psum, off, 16);
    l = l*fs + psum; m = mnew;
    o0*=fs; o1*=fs; o2*=fs; o3*=fs;
    __syncthreads();
    const float* vcol = Vs + c*4;
    const float* prow = ps + r*68;
    for (int j = 0; j < 64; ++j){
      float p = prow[j];
      const float* vr = vcol + j*65;
      o0 += p*vr[0]; o1 += p*vr[1]; o2 += p*vr[2]; o3 += p*vr[3];
    }
  }
  float inv = 1.f / l;
  size_t ob = (size_t)(b*NTOK + qt*16 + r)*256 + h*64 + c*4;
  attno[ob+0]=o0*inv; attno[ob+1]=o1*inv; attno[ob+2]=o2*inv; attno[ob+3]=o3*inv;
}

// ---------------- K5: O-projection + residual ----------------
__global__ __launch_bounds__(256) void k_oproj(const float* __restrict__ attno,
    const float* __restrict__ wo, const float* __restrict__ bo,
    const float* __restrict__ f, float* __restrict__ x1)
{
  __shared__ float orow[256];
  int t = threadIdx.x;
  int pix = blockIdx.x;
  int b = pix / NTOK, n = pix % NTOK;
  orow[t] = attno[(size_t)pix*256 + t];
  __syncthreads();
  const float4* w4 = reinterpret_cast<const float4*>(wo + (size_t)t*256);
  float acc = bo[t];
  #pragma unroll 8
  for (int c4 = 0; c4 < 64; ++c4){
    fma4(w4[c4], orow, c4*4, acc);
  }
  x1[(size_t)pix*256 + t] = acc + f[(size_t)(b*CDIM + t)*NTOK + n];
}

// ---------------- K6: LN + FFN (GELU) + residual; accum adds into mo ----------------
__global__ __launch_bounds__(256) void k_ffn(const float* __restrict__ x1,
    const float* __restrict__ lng, const float* __restrict__ lnb,
    const float* __restrict__ w1, const float* __restrict__ b1,
    const float* __restrict__ w2, const float* __restrict__ b2,
    float* __restrict__ mo, int accum)
{
  __shared__ float xn[256];
  __shared__ float hs[1024];
  __shared__ float red[256];
  int t = threadIdx.x;
  int pix = blockIdx.x;
  float x = x1[(size_t)pix*256 + t];
  float m  = blk_sum256(x,   red) * (1.f/256.f);
  float sq = blk_sum256(x*x, red) * (1.f/256.f);
  float rstd = rsqrtf(sq - m*m + 1e-5f);
  xn[t] = (x - m)*rstd*lng[t] + lnb[t];
  __syncthreads();
  #pragma unroll
  for (int oi = 0; oi < 4; ++oi){
    int o = t*4 + oi;
    const float4* w4 = reinterpret_cast<const float4*>(w1 + (size_t)o*256);
    float acc = b1[o];
    #pragma unroll 8
    for (int c4 = 0; c4 < 64; ++c4){
      fma4(w4[c4], xn, c4*4, acc);
    }
    hs[o] = 0.5f*acc*(1.f + erff(acc*0.70710678118654752f));  // exact GELU
  }
  __syncthreads();
  const float4* w4 = reinterpret_cast<const float4*>(w2 + (size_t)t*1024);
  float acc = b2[t];
  #pragma unroll 8
  for (int c4 = 0; c4 < 256; ++c4){
    fma4(w4[c4], hs, c4*4, acc);
  }
  float v = x + acc;
  size_t oi2 = (size_t)pix*256 + t;
  mo[oi2] = accum ? (mo[oi2] + v) : v;   // ir pass writes, vis pass accumulates
}

// ---------------- K7: scatter-combine into canvas (f32 out) ----------------
__global__ __launch_bounds__(256) void k_combine(const float* __restrict__ fir, const float* __restrict__ fvis,
    const int* __restrict__ sel, const float* __restrict__ msk,
    const float* __restrict__ mo, float* __restrict__ out)
{
  size_t i = (size_t)blockIdx.x*256 + threadIdx.x;   // over B*C*N
  int n = (int)(i % NTOK);
  size_t bc = i / NTOK;
  int cc = (int)(bc % CDIM);
  int b  = (int)(bc / CDIM);
  float base = fir[i] + fvis[i];
  int bn = b*NTOK + n;
  float r;
  if (sel[bn]){
    r = mo[(size_t)bn*256 + cc] * msk[bn];   // mo = ri + rv
  } else {
    r = base;
  }
  out[i] = r;
}

extern "C" void kernel_launch(void* const* d_in, const int* in_sizes, int n_in,
                              void* d_out, int out_size, void* d_ws, size_t ws_size,
                              hipStream_t stream)
{
  // ---- guard (round 6/9 validated n_in & sizes; ws floor known >= 41.5MB) ----
  static const int expected[26] = {
    2359296, 2359296, 262144, 512, 512, 1,
    256, 256, 196608, 768, 65536, 256, 262144, 1024, 262144, 256,
    256, 256, 196608, 768, 65536, 256, 262144, 1024, 262144, 256
  };
  const size_t WS_NEEDED = 37859328;
  float sentinel = 0.f; bool fail = false;
  if (n_in != 26){ sentinel = 1e9f; fail = true; }
  else {
    for (int i = 0; i < 26; ++i){
      if (in_sizes[i] != expected[i]){ sentinel = 1e6f * (float)(i+1); fail = true; break; }
    }
    if (!fail && ws_size < WS_NEEDED){ sentinel = 100.f + (float)(ws_size >> 10); fail = true; }
  }
  if (fail){
    k_fill<<<(out_size + 255)/256, 256, 0, stream>>>((float*)d_out, out_size, sentinel);
    return;
  }

  // All inputs f32 (round-9 evidence: bf16 interpretation caused NaN->OOB aborts;
  // f32 pipeline ran sane; output read as f32).
  const float* fir  = (const float*)d_in[0];
  const float* fvis = (const float*)d_in[1];
  const float* aw1  = (const float*)d_in[2];
  const float* ab1  = (const float*)d_in[3];
  const float* aw2  = (const float*)d_in[4];
  const float* ab2  = (const float*)d_in[5];

  // Workspace layout (37.86 MB, f32, 256B-aligned offsets):
  //   [0)         lf   f32 x 9216
  //   [36864)     msk  f32 x 9216
  //   [73728)     sel  i32 x 9216
  //   [110592)    mo   f32 x 2359296   (ir-FFN writes; vis-FFN accumulates -> ri+rv)
  //   [9547776)   qkv  f32 x 7077888   (x1 f32 x 2359296 ALIASES first 9.4MB:
  //               qkv dead after k_attn; x1 dead before next k_ln_qkv)
  // attno (f32 x 2359296) lives in d_out: dead before k_combine overwrites d_out.
  char* wsb = (char*)d_ws;
  float* lf    = (float*)(wsb + 0);
  float* msk   = (float*)(wsb + 36864);
  int*   sel   = (int*)  (wsb + 73728);
  float* mo    = (float*)(wsb + 110592);
  float* qkv   = (float*)(wsb + 9547776);
  float* x1    = (float*)(wsb + 9547776);   // alias of qkv (see above)
  float* attno = (float*)d_out;             // scratch use of d_out

  k_agent<<<4*NTOK, 256, 0, stream>>>(fir, fvis, aw1, ab1, aw2, ab2, lf);
  k_select<<<4, 256, 0, stream>>>(lf, msk, sel);

  for (int mdl = 0; mdl < 2; ++mdl){
    const float* f = mdl ? fvis : fir;
    int p = 6 + mdl*10;
    const float* lng  = (const float*)d_in[p+0];
    const float* lnb  = (const float*)d_in[p+1];
    const float* wqkv = (const float*)d_in[p+2];
    const float* bqkv = (const float*)d_in[p+3];
    const float* wo   = (const float*)d_in[p+4];
    const float* bo   = (const float*)d_in[p+5];
    const float* w1   = (const float*)d_in[p+6];
    const float* b1   = (const float*)d_in[p+7];
    const float* w2   = (const float*)d_in[p+8];
    const float* b2   = (const float*)d_in[p+9];
    k_ln_qkv<<<4*NTOK, 256, 0, stream>>>(f, lng, lnb, wqkv, bqkv, qkv);
    k_attn  <<<4*NH*(NTOK/16), 256, 0, stream>>>(qkv, sel, attno);
    k_oproj <<<4*NTOK, 256, 0, stream>>>(attno, wo, bo, f, x1);
    k_ffn   <<<4*NTOK, 256, 0, stream>>>(x1, lng, lnb, w1, b1, w2, b2, mo, mdl);
  }

  k_combine<<<(4*CDIM*NTOK)/256, 256, 0, stream>>>(fir, fvis, sel, msk, mo, (float*)d_out);
}

// Round 11
// 8842.924 us; speedup vs baseline: 1.0885x; 1.0885x over previous
//
#include <hip/hip_runtime.h>
#include <hip/hip_bf16.h>
#include <math.h>

#define NTOK 2304
#define CDIM 256
#define NH 4
#define DHD 64

typedef __hip_bfloat16 bf16;

// block-wide sum over 256 threads; all threads receive the result
__device__ __forceinline__ float blk_sum256(float v, float* red){
  int t = threadIdx.x;
  red[t] = v; __syncthreads();
  #pragma unroll
  for (int s = 128; s > 0; s >>= 1){
    if (t < s) red[t] += red[t+s];
    __syncthreads();
  }
  float r = red[0]; __syncthreads();
  return r;
}

__device__ __forceinline__ void fma4(const float4 w, const float* x, int c, float& acc){
  acc += w.x*x[c] + w.y*x[c+1] + w.z*x[c+2] + w.w*x[c+3];
}

// ---------------- K0: sentinel fill (f32) ----------------
__global__ __launch_bounds__(256) void k_fill(float* __restrict__ out, int n, float v){
  int i = blockIdx.x*256 + threadIdx.x;
  if (i < n) out[i] = v;
}

// ---------------- K1: sampling agent logits ----------------
__global__ __launch_bounds__(256) void k_agent(const float* __restrict__ fir, const float* __restrict__ fvis,
    const float* __restrict__ aw1, const float* __restrict__ ab1,
    const float* __restrict__ aw2, const float* __restrict__ ab2,
    float* __restrict__ lf)
{
  __shared__ float xv[512];
  __shared__ float red[256];
  int t = threadIdx.x;
  int pix = blockIdx.x;
  int b = pix / NTOK, n = pix % NTOK;
  xv[t]     = fir [(size_t)(b*CDIM + t)*NTOK + n];
  xv[t+256] = fvis[(size_t)(b*CDIM + t)*NTOK + n];
  __syncthreads();
  float part = 0.f;
  #pragma unroll
  for (int oi = 0; oi < 2; ++oi){
    int o = t + oi*256;
    const float4* w4 = reinterpret_cast<const float4*>(aw1 + (size_t)o*512);
    float acc = ab1[o];
    #pragma unroll 8
    for (int c4 = 0; c4 < 128; ++c4){
      fma4(w4[c4], xv, c4*4, acc);
    }
    float s = acc / (1.f + expf(-acc));   // SiLU
    part += s * aw2[o];
  }
  float tot = blk_sum256(part, red);
  if (t == 0) lf[pix] = tot + ab2[0];
}

// ---------------- K2: selection mask + top-64 fallback (OOB hardened) ----------------
__global__ __launch_bounds__(256) void k_select(const float* __restrict__ lf,
    float* __restrict__ msk, int* __restrict__ sel)
{
  __shared__ float vals[NTOK];
  __shared__ int   ired[256];
  __shared__ float rmax[256];
  __shared__ int   rix[256];
  int b = blockIdx.x;
  int t = threadIdx.x;
  int cnt = 0;
  for (int n = t; n < NTOK; n += 256){
    float v = lf[b*NTOK + n];
    vals[n] = v;
    int m = (v > 0.f) ? 1 : 0;
    msk[b*NTOK + n] = (float)m;
    sel[b*NTOK + n] = m;
    cnt += m;
  }
  ired[t] = cnt; __syncthreads();
  #pragma unroll
  for (int s = 128; s > 0; s >>= 1){
    if (t < s) ired[t] += ired[t+s];
    __syncthreads();
  }
  int count = ired[0];
  __syncthreads();
  if (count < 64){
    for (int n = t; n < NTOK; n += 256) sel[b*NTOK + n] = 0;
    __syncthreads();
    for (int it = 0; it < 64; ++it){
      float bestv = -INFINITY; int besti = t;   // hardened: always valid
      for (int n = t; n < NTOK; n += 256){
        float v = vals[n];
        if (v > bestv || (v == bestv && n < besti)){ bestv = v; besti = n; }
      }
      rmax[t] = bestv; rix[t] = besti; __syncthreads();
      #pragma unroll
      for (int s = 128; s > 0; s >>= 1){
        if (t < s){
          if (rmax[t+s] > rmax[t] || (rmax[t+s] == rmax[t] && rix[t+s] < rix[t])){
            rmax[t] = rmax[t+s]; rix[t] = rix[t+s];
          }
        }
        __syncthreads();
      }
      if (t == 0){
        int w = rix[0];
        if (w >= 0 && w < NTOK){ sel[b*NTOK + w] = 1; vals[w] = -INFINITY; }
      }
      __syncthreads();
    }
  }
}

// ---------------- K3: LN + QKV projection ----------------
__global__ __launch_bounds__(256) void k_ln_qkv(const float* __restrict__ f,
    const float* __restrict__ lng, const float* __restrict__ lnb,
    const float* __restrict__ wqkv, const float* __restrict__ bqkv,
    float* __restrict__ qkv)
{
  __shared__ float xn[256];
  __shared__ float red[256];
  int t = threadIdx.x;
  int pix = blockIdx.x;
  int b = pix / NTOK, n = pix % NTOK;
  float x = f[(size_t)(b*CDIM + t)*NTOK + n];
  float m  = blk_sum256(x,   red) * (1.f/256.f);
  float sq = blk_sum256(x*x, red) * (1.f/256.f);
  float rstd = rsqrtf(sq - m*m + 1e-5f);
  xn[t] = (x - m)*rstd*lng[t] + lnb[t];
  __syncthreads();
  size_t obase = (size_t)pix * 768;
  #pragma unroll
  for (int oi = 0; oi < 3; ++oi){
    int o = t + oi*256;
    const float4* w4 = reinterpret_cast<const float4*>(wqkv + (size_t)o*256);
    float acc = bqkv[o];
    #pragma unroll 8
    for (int c4 = 0; c4 < 64; ++c4){
      fma4(w4[c4], xn, c4*4, acc);
    }
    qkv[obase + o] = acc;
  }
}

// ---------------- K4: masked attention, register-tiled 4x4, float4 LDS ----------------
// Block: 256 threads = 4 waves; 64 q-rows per block (wave w owns rows [w*16,(w+1)*16)).
// Lane (w,l): qh=l>>4, kg=l&15. Lane's q rows: w*16+qh+4i (i=0..3).
// Lane's k cols: kg+16j (j=0..3). Lane's output dims: kg*4..kg*4+3.
// LDS strides of 68 floats keep all b128 patterns <=2-way bank aliased.
__global__ __launch_bounds__(256) void k_attn(const float* __restrict__ qkv,
    const int* __restrict__ sel, float* __restrict__ attno)
{
  __shared__ float Qs[64*68];
  __shared__ float Ks[64*68];
  __shared__ float Vs[64*68];
  __shared__ float Ps[64*68];
  __shared__ int selk[64];
  int tid = threadIdx.x;
  int w  = tid >> 6;
  int l  = tid & 63;
  int kg = l & 15;
  int qh = l >> 4;
  int qbase = w*16 + qh;     // + 4*i
  int bi = blockIdx.x;
  int qt = bi % 36; int h = (bi/36) % NH; int b = bi / (36*NH);

  // stage Q tile (64 rows x 64 dims), float4, coalesced
  for (int c = tid; c < 1024; c += 256){
    int r = c >> 4, d4 = c & 15;
    float4 v = *(const float4*)(qkv + (size_t)(b*NTOK + qt*64 + r)*768 + h*64 + d4*4);
    *(float4*)(Qs + r*68 + d4*4) = v;
  }

  float m_[4], l_[4], o_[4][4];
  #pragma unroll
  for (int i = 0; i < 4; ++i){
    m_[i] = -INFINITY; l_[i] = 0.f;
    o_[i][0]=0.f; o_[i][1]=0.f; o_[i][2]=0.f; o_[i][3]=0.f;
  }

  for (int kt = 0; kt < 36; ++kt){
    __syncthreads();   // prev-tile LDS reads done (also covers Q staging on kt=0)
    for (int c = tid; c < 1024; c += 256){
      int r = c >> 4, d4 = c & 15;
      size_t base = (size_t)(b*NTOK + kt*64 + r)*768 + h*64 + d4*4;
      *(float4*)(Ks + r*68 + d4*4) = *(const float4*)(qkv + base + 256);
      *(float4*)(Vs + r*68 + d4*4) = *(const float4*)(qkv + base + 512);
    }
    if (tid < 64) selk[tid] = sel[b*NTOK + kt*64 + tid];
    __syncthreads();

    // ---- QK^T: s[i][j], contraction over d in float4 chunks ----
    float s[4][4];
    #pragma unroll
    for (int i = 0; i < 4; ++i){ s[i][0]=0.f; s[i][1]=0.f; s[i][2]=0.f; s[i][3]=0.f; }
    #pragma unroll 4
    for (int d4 = 0; d4 < 16; ++d4){
      float4 qv[4], kv[4];
      #pragma unroll
      for (int i = 0; i < 4; ++i) qv[i] = *(const float4*)(Qs + (qbase+4*i)*68 + d4*4);
      #pragma unroll
      for (int j = 0; j < 4; ++j) kv[j] = *(const float4*)(Ks + (kg+16*j)*68 + d4*4);
      #pragma unroll
      for (int i = 0; i < 4; ++i){
        #pragma unroll
        for (int j = 0; j < 4; ++j){
          s[i][j] += qv[i].x*kv[j].x + qv[i].y*kv[j].y + qv[i].z*kv[j].z + qv[i].w*kv[j].w;
        }
      }
    }
    // mask + scale
    int ms0 = selk[kg], ms1 = selk[kg+16], ms2 = selk[kg+32], ms3 = selk[kg+48];
    #pragma unroll
    for (int i = 0; i < 4; ++i){
      s[i][0] = ms0 ? s[i][0]*0.125f : -1e9f;
      s[i][1] = ms1 ? s[i][1]*0.125f : -1e9f;
      s[i][2] = ms2 ? s[i][2]*0.125f : -1e9f;
      s[i][3] = ms3 ? s[i][3]*0.125f : -1e9f;
    }
    // online softmax per q-row (row lives in the 16 lanes sharing (w,qh))
    float p[4][4];
    #pragma unroll
    for (int i = 0; i < 4; ++i){
      float mx = fmaxf(fmaxf(s[i][0], s[i][1]), fmaxf(s[i][2], s[i][3]));
      #pragma unroll
      for (int off = 8; off; off >>= 1) mx = fmaxf(mx, __shfl_xor(mx, off, 16));
      float mnew = fmaxf(m_[i], mx);
      float fs = expf(m_[i] - mnew);
      p[i][0] = expf(s[i][0] - mnew); p[i][1] = expf(s[i][1] - mnew);
      p[i][2] = expf(s[i][2] - mnew); p[i][3] = expf(s[i][3] - mnew);
      float ps = p[i][0] + p[i][1] + p[i][2] + p[i][3];
      #pragma unroll
      for (int off = 8; off; off >>= 1) ps += __shfl_xor(ps, off, 16);
      l_[i] = l_[i]*fs + ps; m_[i] = mnew;
      o_[i][0]*=fs; o_[i][1]*=fs; o_[i][2]*=fs; o_[i][3]*=fs;
    }
    // write P (stays within this wave's 16-row band -> no barrier needed)
    #pragma unroll
    for (int i = 0; i < 4; ++i){
      Ps[(qbase+4*i)*68 + kg     ] = p[i][0];
      Ps[(qbase+4*i)*68 + kg + 16] = p[i][1];
      Ps[(qbase+4*i)*68 + kg + 32] = p[i][2];
      Ps[(qbase+4*i)*68 + kg + 48] = p[i][3];
    }
    // ---- PV: o[i][dd] += sum_k P[qrow][k] * V[k][kg*4+dd] ----
    #pragma unroll 4
    for (int k4 = 0; k4 < 16; ++k4){
      float4 pv[4], vv[4];
      #pragma unroll
      for (int i = 0; i < 4; ++i) pv[i] = *(const float4*)(Ps + (qbase+4*i)*68 + k4*4);
      #pragma unroll
      for (int jj = 0; jj < 4; ++jj) vv[jj] = *(const float4*)(Vs + (k4*4+jj)*68 + kg*4);
      #pragma unroll
      for (int i = 0; i < 4; ++i){
        o_[i][0] += pv[i].x*vv[0].x + pv[i].y*vv[1].x + pv[i].z*vv[2].x + pv[i].w*vv[3].x;
        o_[i][1] += pv[i].x*vv[0].y + pv[i].y*vv[1].y + pv[i].z*vv[2].y + pv[i].w*vv[3].y;
        o_[i][2] += pv[i].x*vv[0].z + pv[i].y*vv[1].z + pv[i].z*vv[2].z + pv[i].w*vv[3].z;
        o_[i][3] += pv[i].x*vv[0].w + pv[i].y*vv[1].w + pv[i].z*vv[2].w + pv[i].w*vv[3].w;
      }
    }
  }
  // epilogue: normalize, write float4 per row
  #pragma unroll
  for (int i = 0; i < 4; ++i){
    float inv = 1.f / l_[i];
    int row = qt*64 + qbase + 4*i;
    float4 ov; ov.x = o_[i][0]*inv; ov.y = o_[i][1]*inv; ov.z = o_[i][2]*inv; ov.w = o_[i][3]*inv;
    *(float4*)(attno + (size_t)(b*NTOK + row)*256 + h*64 + kg*4) = ov;
  }
}

// ---------------- K5: O-projection + residual ----------------
__global__ __launch_bounds__(256) void k_oproj(const float* __restrict__ attno,
    const float* __restrict__ wo, const float* __restrict__ bo,
    const float* __restrict__ f, float* __restrict__ x1)
{
  __shared__ float orow[256];
  int t = threadIdx.x;
  int pix = blockIdx.x;
  int b = pix / NTOK, n = pix % NTOK;
  orow[t] = attno[(size_t)pix*256 + t];
  __syncthreads();
  const float4* w4 = reinterpret_cast<const float4*>(wo + (size_t)t*256);
  float acc = bo[t];
  #pragma unroll 8
  for (int c4 = 0; c4 < 64; ++c4){
    fma4(w4[c4], orow, c4*4, acc);
  }
  x1[(size_t)pix*256 + t] = acc + f[(size_t)(b*CDIM + t)*NTOK + n];
}

// ---------------- K6: LN + FFN (GELU) + residual; accum adds into mo ----------------
__global__ __launch_bounds__(256) void k_ffn(const float* __restrict__ x1,
    const float* __restrict__ lng, const float* __restrict__ lnb,
    const float* __restrict__ w1, const float* __restrict__ b1,
    const float* __restrict__ w2, const float* __restrict__ b2,
    float* __restrict__ mo, int accum)
{
  __shared__ float xn[256];
  __shared__ float hs[1024];
  __shared__ float red[256];
  int t = threadIdx.x;
  int pix = blockIdx.x;
  float x = x1[(size_t)pix*256 + t];
  float m  = blk_sum256(x,   red) * (1.f/256.f);
  float sq = blk_sum256(x*x, red) * (1.f/256.f);
  float rstd = rsqrtf(sq - m*m + 1e-5f);
  xn[t] = (x - m)*rstd*lng[t] + lnb[t];
  __syncthreads();
  #pragma unroll
  for (int oi = 0; oi < 4; ++oi){
    int o = t*4 + oi;
    const float4* w4 = reinterpret_cast<const float4*>(w1 + (size_t)o*256);
    float acc = b1[o];
    #pragma unroll 8
    for (int c4 = 0; c4 < 64; ++c4){
      fma4(w4[c4], xn, c4*4, acc);
    }
    hs[o] = 0.5f*acc*(1.f + erff(acc*0.70710678118654752f));  // exact GELU
  }
  __syncthreads();
  const float4* w4 = reinterpret_cast<const float4*>(w2 + (size_t)t*1024);
  float acc = b2[t];
  #pragma unroll 8
  for (int c4 = 0; c4 < 256; ++c4){
    fma4(w4[c4], hs, c4*4, acc);
  }
  float v = x + acc;
  size_t oi2 = (size_t)pix*256 + t;
  mo[oi2] = accum ? (mo[oi2] + v) : v;   // ir pass writes, vis pass accumulates
}

// ---------------- K7: scatter-combine into canvas (f32 out) ----------------
__global__ __launch_bounds__(256) void k_combine(const float* __restrict__ fir, const float* __restrict__ fvis,
    const int* __restrict__ sel, const float* __restrict__ msk,
    const float* __restrict__ mo, float* __restrict__ out)
{
  size_t i = (size_t)blockIdx.x*256 + threadIdx.x;   // over B*C*N
  int n = (int)(i % NTOK);
  size_t bc = i / NTOK;
  int cc = (int)(bc % CDIM);
  int b  = (int)(bc / CDIM);
  float base = fir[i] + fvis[i];
  int bn = b*NTOK + n;
  float r;
  if (sel[bn]){
    r = mo[(size_t)bn*256 + cc] * msk[bn];   // mo = ri + rv
  } else {
    r = base;
  }
  out[i] = r;
}

extern "C" void kernel_launch(void* const* d_in, const int* in_sizes, int n_in,
                              void* d_out, int out_size, void* d_ws, size_t ws_size,
                              hipStream_t stream)
{
  static const int expected[26] = {
    2359296, 2359296, 262144, 512, 512, 1,
    256, 256, 196608, 768, 65536, 256, 262144, 1024, 262144, 256,
    256, 256, 196608, 768, 65536, 256, 262144, 1024, 262144, 256
  };
  const size_t WS_NEEDED = 37859328;
  float sentinel = 0.f; bool fail = false;
  if (n_in != 26){ sentinel = 1e9f; fail = true; }
  else {
    for (int i = 0; i < 26; ++i){
      if (in_sizes[i] != expected[i]){ sentinel = 1e6f * (float)(i+1); fail = true; break; }
    }
    if (!fail && ws_size < WS_NEEDED){ sentinel = 100.f + (float)(ws_size >> 10); fail = true; }
  }
  if (fail){
    k_fill<<<(out_size + 255)/256, 256, 0, stream>>>((float*)d_out, out_size, sentinel);
    return;
  }

  const float* fir  = (const float*)d_in[0];
  const float* fvis = (const float*)d_in[1];
  const float* aw1  = (const float*)d_in[2];
  const float* ab1  = (const float*)d_in[3];
  const float* aw2  = (const float*)d_in[4];
  const float* ab2  = (const float*)d_in[5];

  // Workspace layout (37.86 MB, f32, 256B-aligned offsets):
  //   [0)         lf   f32 x 9216
  //   [36864)     msk  f32 x 9216
  //   [73728)     sel  i32 x 9216
  //   [110592)    mo   f32 x 2359296   (ir-FFN writes; vis-FFN accumulates -> ri+rv)
  //   [9547776)   qkv  f32 x 7077888   (x1 f32 x 2359296 ALIASES first 9.4MB:
  //               qkv dead after k_attn; x1 dead before next k_ln_qkv)
  // attno (f32 x 2359296) lives in d_out: dead before k_combine overwrites d_out.
  char* wsb = (char*)d_ws;
  float* lf    = (float*)(wsb + 0);
  float* msk   = (float*)(wsb + 36864);
  int*   sel   = (int*)  (wsb + 73728);
  float* mo    = (float*)(wsb + 110592);
  float* qkv   = (float*)(wsb + 9547776);
  float* x1    = (float*)(wsb + 9547776);   // alias of qkv (see above)
  float* attno = (float*)d_out;             // scratch use of d_out

  k_agent<<<4*NTOK, 256, 0, stream>>>(fir, fvis, aw1, ab1, aw2, ab2, lf);
  k_select<<<4, 256, 0, stream>>>(lf, msk, sel);

  for (int mdl = 0; mdl < 2; ++mdl){
    const float* f = mdl ? fvis : fir;
    int p = 6 + mdl*10;
    const float* lng  = (const float*)d_in[p+0];
    const float* lnb  = (const float*)d_in[p+1];
    const float* wqkv = (const float*)d_in[p+2];
    const float* bqkv = (const float*)d_in[p+3];
    const float* wo   = (const float*)d_in[p+4];
    const float* bo   = (const float*)d_in[p+5];
    const float* w1   = (const float*)d_in[p+6];
    const float* b1   = (const float*)d_in[p+7];
    const float* w2   = (const float*)d_in[p+8];
    const float* b2   = (const float*)d_in[p+9];
    k_ln_qkv<<<4*NTOK, 256, 0, stream>>>(f, lng, lnb, wqkv, bqkv, qkv);
    k_attn  <<<4*NH*(NTOK/64), 256, 0, stream>>>(qkv, sel, attno);
    k_oproj <<<4*NTOK, 256, 0, stream>>>(attno, wo, bo, f, x1);
    k_ffn   <<<4*NTOK, 256, 0, stream>>>(x1, lng, lnb, w1, b1, w2, b2, mo, mdl);
  }

  k_combine<<<(4*CDIM*NTOK)/256, 256, 0, stream>>>(fir, fvis, sel, msk, mo, (float*)d_out);
}

// Round 12
// 5201.178 us; speedup vs baseline: 1.8506x; 1.7002x over previous
//
#include <hip/hip_runtime.h>
#include <hip/hip_bf16.h>
#include <math.h>

#define NTOK 2304
#define CDIM 256
#define NH 4
#define DHD 64

typedef __hip_bfloat16 bf16;

// block-wide sum over 256 threads; all threads receive the result
__device__ __forceinline__ float blk_sum256(float v, float* red){
  int t = threadIdx.x;
  red[t] = v; __syncthreads();
  #pragma unroll
  for (int s = 128; s > 0; s >>= 1){
    if (t < s) red[t] += red[t+s];
    __syncthreads();
  }
  float r = red[0]; __syncthreads();
  return r;
}

__device__ __forceinline__ void fma4(const float4 w, const float* x, int c, float& acc){
  acc += w.x*x[c] + w.y*x[c+1] + w.z*x[c+2] + w.w*x[c+3];
}

__device__ __forceinline__ float bfu(unsigned short s){
  union{unsigned u; float f;} a; a.u = ((unsigned)s)<<16; return a.f;
}

// ---------------- K0: sentinel fill (f32) ----------------
__global__ __launch_bounds__(256) void k_fill(float* __restrict__ out, int n, float v){
  int i = blockIdx.x*256 + threadIdx.x;
  if (i < n) out[i] = v;
}

// ---------------- K1: sampling agent logits ----------------
__global__ __launch_bounds__(256) void k_agent(const float* __restrict__ fir, const float* __restrict__ fvis,
    const float* __restrict__ aw1, const float* __restrict__ ab1,
    const float* __restrict__ aw2, const float* __restrict__ ab2,
    float* __restrict__ lf)
{
  __shared__ float xv[512];
  __shared__ float red[256];
  int t = threadIdx.x;
  int pix = blockIdx.x;
  int b = pix / NTOK, n = pix % NTOK;
  xv[t]     = fir [(size_t)(b*CDIM + t)*NTOK + n];
  xv[t+256] = fvis[(size_t)(b*CDIM + t)*NTOK + n];
  __syncthreads();
  float part = 0.f;
  #pragma unroll
  for (int oi = 0; oi < 2; ++oi){
    int o = t + oi*256;
    const float4* w4 = reinterpret_cast<const float4*>(aw1 + (size_t)o*512);
    float acc = ab1[o];
    #pragma unroll 8
    for (int c4 = 0; c4 < 128; ++c4){
      fma4(w4[c4], xv, c4*4, acc);
    }
    float s = acc / (1.f + expf(-acc));   // SiLU
    part += s * aw2[o];
  }
  float tot = blk_sum256(part, red);
  if (t == 0) lf[pix] = tot + ab2[0];
}

// ---------------- K2: selection mask + top-64 fallback (OOB hardened) ----------------
__global__ __launch_bounds__(256) void k_select(const float* __restrict__ lf,
    float* __restrict__ msk, int* __restrict__ sel)
{
  __shared__ float vals[NTOK];
  __shared__ int   ired[256];
  __shared__ float rmax[256];
  __shared__ int   rix[256];
  int b = blockIdx.x;
  int t = threadIdx.x;
  int cnt = 0;
  for (int n = t; n < NTOK; n += 256){
    float v = lf[b*NTOK + n];
    vals[n] = v;
    int m = (v > 0.f) ? 1 : 0;
    msk[b*NTOK + n] = (float)m;
    sel[b*NTOK + n] = m;
    cnt += m;
  }
  ired[t] = cnt; __syncthreads();
  #pragma unroll
  for (int s = 128; s > 0; s >>= 1){
    if (t < s) ired[t] += ired[t+s];
    __syncthreads();
  }
  int count = ired[0];
  __syncthreads();
  if (count < 64){
    for (int n = t; n < NTOK; n += 256) sel[b*NTOK + n] = 0;
    __syncthreads();
    for (int it = 0; it < 64; ++it){
      float bestv = -INFINITY; int besti = t;
      for (int n = t; n < NTOK; n += 256){
        float v = vals[n];
        if (v > bestv || (v == bestv && n < besti)){ bestv = v; besti = n; }
      }
      rmax[t] = bestv; rix[t] = besti; __syncthreads();
      #pragma unroll
      for (int s = 128; s > 0; s >>= 1){
        if (t < s){
          if (rmax[t+s] > rmax[t] || (rmax[t+s] == rmax[t] && rix[t+s] < rix[t])){
            rmax[t] = rmax[t+s]; rix[t] = rix[t+s];
          }
        }
        __syncthreads();
      }
      if (t == 0){
        int w = rix[0];
        if (w >= 0 && w < NTOK){ sel[b*NTOK + w] = 1; vals[w] = -INFINITY; }
      }
      __syncthreads();
    }
  }
}

// ---------------- K3: LN + QKV projection ----------------
__global__ __launch_bounds__(256) void k_ln_qkv(const float* __restrict__ f,
    const float* __restrict__ lng, const float* __restrict__ lnb,
    const float* __restrict__ wqkv, const float* __restrict__ bqkv,
    float* __restrict__ qkv)
{
  __shared__ float xn[256];
  __shared__ float red[256];
  int t = threadIdx.x;
  int pix = blockIdx.x;
  int b = pix / NTOK, n = pix % NTOK;
  float x = f[(size_t)(b*CDIM + t)*NTOK + n];
  float m  = blk_sum256(x,   red) * (1.f/256.f);
  float sq = blk_sum256(x*x, red) * (1.f/256.f);
  float rstd = rsqrtf(sq - m*m + 1e-5f);
  xn[t] = (x - m)*rstd*lng[t] + lnb[t];
  __syncthreads();
  size_t obase = (size_t)pix * 768;
  #pragma unroll
  for (int oi = 0; oi < 3; ++oi){
    int o = t + oi*256;
    const float4* w4 = reinterpret_cast<const float4*>(wqkv + (size_t)o*256);
    float acc = bqkv[o];
    #pragma unroll 8
    for (int c4 = 0; c4 < 64; ++c4){
      fma4(w4[c4], xn, c4*4, acc);
    }
    qkv[obase + o] = acc;
  }
}

// ---------------- K4: masked attention, register-tiled 4x4, float4 LDS ----------------
__global__ __launch_bounds__(256) void k_attn(const float* __restrict__ qkv,
    const int* __restrict__ sel, float* __restrict__ attno)
{
  __shared__ float Qs[64*68];
  __shared__ float Ks[64*68];
  __shared__ float Vs[64*68];
  __shared__ float Ps[64*68];
  __shared__ int selk[64];
  int tid = threadIdx.x;
  int w  = tid >> 6;
  int l  = tid & 63;
  int kg = l & 15;
  int qh = l >> 4;
  int qbase = w*16 + qh;     // + 4*i
  int bi = blockIdx.x;
  int qt = bi % 36; int h = (bi/36) % NH; int b = bi / (36*NH);

  for (int c = tid; c < 1024; c += 256){
    int r = c >> 4, d4 = c & 15;
    float4 v = *(const float4*)(qkv + (size_t)(b*NTOK + qt*64 + r)*768 + h*64 + d4*4);
    *(float4*)(Qs + r*68 + d4*4) = v;
  }

  float m_[4], l_[4], o_[4][4];
  #pragma unroll
  for (int i = 0; i < 4; ++i){
    m_[i] = -INFINITY; l_[i] = 0.f;
    o_[i][0]=0.f; o_[i][1]=0.f; o_[i][2]=0.f; o_[i][3]=0.f;
  }

  for (int kt = 0; kt < 36; ++kt){
    __syncthreads();
    for (int c = tid; c < 1024; c += 256){
      int r = c >> 4, d4 = c & 15;
      size_t base = (size_t)(b*NTOK + kt*64 + r)*768 + h*64 + d4*4;
      *(float4*)(Ks + r*68 + d4*4) = *(const float4*)(qkv + base + 256);
      *(float4*)(Vs + r*68 + d4*4) = *(const float4*)(qkv + base + 512);
    }
    if (tid < 64) selk[tid] = sel[b*NTOK + kt*64 + tid];
    __syncthreads();

    float s[4][4];
    #pragma unroll
    for (int i = 0; i < 4; ++i){ s[i][0]=0.f; s[i][1]=0.f; s[i][2]=0.f; s[i][3]=0.f; }
    #pragma unroll 4
    for (int d4 = 0; d4 < 16; ++d4){
      float4 qv[4], kv[4];
      #pragma unroll
      for (int i = 0; i < 4; ++i) qv[i] = *(const float4*)(Qs + (qbase+4*i)*68 + d4*4);
      #pragma unroll
      for (int j = 0; j < 4; ++j) kv[j] = *(const float4*)(Ks + (kg+16*j)*68 + d4*4);
      #pragma unroll
      for (int i = 0; i < 4; ++i){
        #pragma unroll
        for (int j = 0; j < 4; ++j){
          s[i][j] += qv[i].x*kv[j].x + qv[i].y*kv[j].y + qv[i].z*kv[j].z + qv[i].w*kv[j].w;
        }
      }
    }
    int ms0 = selk[kg], ms1 = selk[kg+16], ms2 = selk[kg+32], ms3 = selk[kg+48];
    #pragma unroll
    for (int i = 0; i < 4; ++i){
      s[i][0] = ms0 ? s[i][0]*0.125f : -1e9f;
      s[i][1] = ms1 ? s[i][1]*0.125f : -1e9f;
      s[i][2] = ms2 ? s[i][2]*0.125f : -1e9f;
      s[i][3] = ms3 ? s[i][3]*0.125f : -1e9f;
    }
    float p[4][4];
    #pragma unroll
    for (int i = 0; i < 4; ++i){
      float mx = fmaxf(fmaxf(s[i][0], s[i][1]), fmaxf(s[i][2], s[i][3]));
      #pragma unroll
      for (int off = 8; off; off >>= 1) mx = fmaxf(mx, __shfl_xor(mx, off, 16));
      float mnew = fmaxf(m_[i], mx);
      float fs = expf(m_[i] - mnew);
      p[i][0] = expf(s[i][0] - mnew); p[i][1] = expf(s[i][1] - mnew);
      p[i][2] = expf(s[i][2] - mnew); p[i][3] = expf(s[i][3] - mnew);
      float ps = p[i][0] + p[i][1] + p[i][2] + p[i][3];
      #pragma unroll
      for (int off = 8; off; off >>= 1) ps += __shfl_xor(ps, off, 16);
      l_[i] = l_[i]*fs + ps; m_[i] = mnew;
      o_[i][0]*=fs; o_[i][1]*=fs; o_[i][2]*=fs; o_[i][3]*=fs;
    }
    #pragma unroll
    for (int i = 0; i < 4; ++i){
      Ps[(qbase+4*i)*68 + kg     ] = p[i][0];
      Ps[(qbase+4*i)*68 + kg + 16] = p[i][1];
      Ps[(qbase+4*i)*68 + kg + 32] = p[i][2];
      Ps[(qbase+4*i)*68 + kg + 48] = p[i][3];
    }
    #pragma unroll 4
    for (int k4 = 0; k4 < 16; ++k4){
      float4 pv[4], vv[4];
      #pragma unroll
      for (int i = 0; i < 4; ++i) pv[i] = *(const float4*)(Ps + (qbase+4*i)*68 + k4*4);
      #pragma unroll
      for (int jj = 0; jj < 4; ++jj) vv[jj] = *(const float4*)(Vs + (k4*4+jj)*68 + kg*4);
      #pragma unroll
      for (int i = 0; i < 4; ++i){
        o_[i][0] += pv[i].x*vv[0].x + pv[i].y*vv[1].x + pv[i].z*vv[2].x + pv[i].w*vv[3].x;
        o_[i][1] += pv[i].x*vv[0].y + pv[i].y*vv[1].y + pv[i].z*vv[2].y + pv[i].w*vv[3].y;
        o_[i][2] += pv[i].x*vv[0].z + pv[i].y*vv[1].z + pv[i].z*vv[2].z + pv[i].w*vv[3].z;
        o_[i][3] += pv[i].x*vv[0].w + pv[i].y*vv[1].w + pv[i].z*vv[2].w + pv[i].w*vv[3].w;
      }
    }
  }
  #pragma unroll
  for (int i = 0; i < 4; ++i){
    float inv = 1.f / l_[i];
    int row = qt*64 + qbase + 4*i;
    float4 ov; ov.x = o_[i][0]*inv; ov.y = o_[i][1]*inv; ov.z = o_[i][2]*inv; ov.w = o_[i][3]*inv;
    *(float4*)(attno + (size_t)(b*NTOK + row)*256 + h*64 + kg*4) = ov;
  }
}

// ---------------- K5: O-projection + residual + fused LN (xn for FFN) ----------------
__global__ __launch_bounds__(256) void k_oproj_ln(const float* __restrict__ attno,
    const float* __restrict__ wo, const float* __restrict__ bo,
    const float* __restrict__ f,
    const float* __restrict__ lng, const float* __restrict__ lnb,
    float* __restrict__ x1, float* __restrict__ xn_out)
{
  __shared__ float orow[256];
  __shared__ float red[256];
  int t = threadIdx.x;
  int pix = blockIdx.x;
  int b = pix / NTOK, n = pix % NTOK;
  orow[t] = attno[(size_t)pix*256 + t];
  __syncthreads();
  const float4* w4 = reinterpret_cast<const float4*>(wo + (size_t)t*256);
  float acc = bo[t];
  #pragma unroll 8
  for (int c4 = 0; c4 < 64; ++c4){
    fma4(w4[c4], orow, c4*4, acc);
  }
  float v = acc + f[(size_t)(b*CDIM + t)*NTOK + n];
  x1[(size_t)pix*256 + t] = v;
  // fused LN (for the FFN input); xn_out aliases attno's storage (d_out) -
  // safe: this block already consumed attno[pix*256..] into LDS above.
  float m  = blk_sum256(v,   red) * (1.f/256.f);
  float sq = blk_sum256(v*v, red) * (1.f/256.f);
  float rstd = rsqrtf(sq - m*m + 1e-5f);
  xn_out[(size_t)pix*256 + t] = (v - m)*rstd*lng[t] + lnb[t];
}

// ---------------- K6a: GEMM1 H = gelu(xn . W1^T + b1), bf16 out ----------------
// 64px x 64h tiles; 4x4 register tile per thread with interleaved rows (pi+16i)
// -> <=2-way LDS bank aliasing on b128 reads (free).
__global__ __launch_bounds__(256) void k_gemm1(const float* __restrict__ xn,
    const float* __restrict__ w1, const float* __restrict__ b1,
    bf16* __restrict__ H)
{
  __shared__ float Xs[64*68];
  __shared__ float Ws[64*68];
  int tid = threadIdx.x;
  int bp = blockIdx.x % 144, bh = blockIdx.x / 144;
  int pi = tid & 15, hj = tid >> 4;
  float acc[4][4] = {{0.f}};
  for (int k0 = 0; k0 < 256; k0 += 64){
    __syncthreads();
    for (int c = tid; c < 1024; c += 256){
      int r = c >> 4, f4 = c & 15;
      *(float4*)(Xs + r*68 + f4*4) = *(const float4*)(xn + (size_t)(bp*64 + r)*256 + k0 + f4*4);
      *(float4*)(Ws + r*68 + f4*4) = *(const float4*)(w1 + (size_t)(bh*64 + r)*256 + k0 + f4*4);
    }
    __syncthreads();
    #pragma unroll 4
    for (int k4 = 0; k4 < 16; ++k4){
      float4 xv[4], wv[4];
      #pragma unroll
      for (int i = 0; i < 4; ++i) xv[i] = *(const float4*)(Xs + (pi+16*i)*68 + k4*4);
      #pragma unroll
      for (int j = 0; j < 4; ++j) wv[j] = *(const float4*)(Ws + (hj+16*j)*68 + k4*4);
      #pragma unroll
      for (int i = 0; i < 4; ++i){
        #pragma unroll
        for (int j = 0; j < 4; ++j){
          acc[i][j] += xv[i].x*wv[j].x + xv[i].y*wv[j].y + xv[i].z*wv[j].z + xv[i].w*wv[j].w;
        }
      }
    }
  }
  #pragma unroll
  for (int i = 0; i < 4; ++i){
    int p = bp*64 + pi + 16*i;
    #pragma unroll
    for (int j = 0; j < 4; ++j){
      int hh = bh*64 + hj + 16*j;
      float v = acc[i][j] + b1[hh];
      v = 0.5f*v*(1.f + erff(v*0.70710678118654752f));
      H[(size_t)p*1024 + hh] = __float2bfloat16(v);
    }
  }
}

// ---------------- K6b: GEMM2 mo (+)= x1 + H . W2^T + b2 ----------------
__global__ __launch_bounds__(256) void k_gemm2(const bf16* __restrict__ H,
    const float* __restrict__ w2, const float* __restrict__ b2,
    const float* __restrict__ x1, float* __restrict__ mo, int accum)
{
  __shared__ float Hs[64*68];
  __shared__ float Ws[64*68];
  int tid = threadIdx.x;
  int bp = blockIdx.x % 144, bo = blockIdx.x / 144;  // bo in 0..3
  int pi = tid & 15, oj = tid >> 4;
  float acc[4][4] = {{0.f}};
  for (int k0 = 0; k0 < 1024; k0 += 64){
    __syncthreads();
    for (int c = tid; c < 1024; c += 256){
      int r = c >> 4, f4 = c & 15;
      const ushort4 u = *(const ushort4*)(H + (size_t)(bp*64 + r)*1024 + k0 + f4*4);
      float4 hv; hv.x = bfu(u.x); hv.y = bfu(u.y); hv.z = bfu(u.z); hv.w = bfu(u.w);
      *(float4*)(Hs + r*68 + f4*4) = hv;
      *(float4*)(Ws + r*68 + f4*4) = *(const float4*)(w2 + (size_t)(bo*64 + r)*1024 + k0 + f4*4);
    }
    __syncthreads();
    #pragma unroll 4
    for (int k4 = 0; k4 < 16; ++k4){
      float4 hv[4], wv[4];
      #pragma unroll
      for (int i = 0; i < 4; ++i) hv[i] = *(const float4*)(Hs + (pi+16*i)*68 + k4*4);
      #pragma unroll
      for (int j = 0; j < 4; ++j) wv[j] = *(const float4*)(Ws + (oj+16*j)*68 + k4*4);
      #pragma unroll
      for (int i = 0; i < 4; ++i){
        #pragma unroll
        for (int j = 0; j < 4; ++j){
          acc[i][j] += hv[i].x*wv[j].x + hv[i].y*wv[j].y + hv[i].z*wv[j].z + hv[i].w*wv[j].w;
        }
      }
    }
  }
  #pragma unroll
  for (int i = 0; i < 4; ++i){
    int p = bp*64 + pi + 16*i;
    #pragma unroll
    for (int j = 0; j < 4; ++j){
      int o = bo*64 + oj + 16*j;
      size_t idx = (size_t)p*256 + o;
      float v = acc[i][j] + b2[o] + x1[idx];
      mo[idx] = accum ? (mo[idx] + v) : v;
    }
  }
}

// ---------------- K7: scatter-combine into canvas (f32 out) ----------------
__global__ __launch_bounds__(256) void k_combine(const float* __restrict__ fir, const float* __restrict__ fvis,
    const int* __restrict__ sel, const float* __restrict__ msk,
    const float* __restrict__ mo, float* __restrict__ out)
{
  size_t i = (size_t)blockIdx.x*256 + threadIdx.x;
  int n = (int)(i % NTOK);
  size_t bc = i / NTOK;
  int cc = (int)(bc % CDIM);
  int b  = (int)(bc / CDIM);
  float base = fir[i] + fvis[i];
  int bn = b*NTOK + n;
  float r;
  if (sel[bn]){
    r = mo[(size_t)bn*256 + cc] * msk[bn];
  } else {
    r = base;
  }
  out[i] = r;
}

extern "C" void kernel_launch(void* const* d_in, const int* in_sizes, int n_in,
                              void* d_out, int out_size, void* d_ws, size_t ws_size,
                              hipStream_t stream)
{
  static const int expected[26] = {
    2359296, 2359296, 262144, 512, 512, 1,
    256, 256, 196608, 768, 65536, 256, 262144, 1024, 262144, 256,
    256, 256, 196608, 768, 65536, 256, 262144, 1024, 262144, 256
  };
  const size_t WS_NEEDED = 37859328;
  float sentinel = 0.f; bool fail = false;
  if (n_in != 26){ sentinel = 1e9f; fail = true; }
  else {
    for (int i = 0; i < 26; ++i){
      if (in_sizes[i] != expected[i]){ sentinel = 1e6f * (float)(i+1); fail = true; break; }
    }
    if (!fail && ws_size < WS_NEEDED){ sentinel = 100.f + (float)(ws_size >> 10); fail = true; }
  }
  if (fail){
    k_fill<<<(out_size + 255)/256, 256, 0, stream>>>((float*)d_out, out_size, sentinel);
    return;
  }

  const float* fir  = (const float*)d_in[0];
  const float* fvis = (const float*)d_in[1];
  const float* aw1  = (const float*)d_in[2];
  const float* ab1  = (const float*)d_in[3];
  const float* aw2  = (const float*)d_in[4];
  const float* ab2  = (const float*)d_in[5];

  // Workspace layout (37.86 MB, unchanged):
  //   [0)         lf   f32 x 9216
  //   [36864)     msk  f32 x 9216
  //   [73728)     sel  i32 x 9216
  //   [110592)    mo   f32 x 2359296   (ir writes; vis accumulates -> ri+rv)
  //   [9547776)   qkv  f32 x 7077888   region, multiplexed in time:
  //      x1 (f32 x 2359296, 9.44MB)  = first part  (live after attn consumed qkv)
  //      H  (bf16 x 9216x1024, 18.9MB) = remaining  (live during gemm1/gemm2)
  // attno AND xn live in d_out (attno dead once oproj stages it; xn dead after
  // gemm1; combine overwrites d_out at the end).
  char* wsb = (char*)d_ws;
  float* lf    = (float*)(wsb + 0);
  float* msk   = (float*)(wsb + 36864);
  int*   sel   = (int*)  (wsb + 73728);
  float* mo    = (float*)(wsb + 110592);
  float* qkv   = (float*)(wsb + 9547776);
  float* x1    = (float*)(wsb + 9547776);           // alias: qkv dead after attn
  bf16*  H     = (bf16*) (wsb + 9547776 + 9437184); // alias: tail of qkv region
  float* attno = (float*)d_out;                     // scratch use of d_out
  float* xn    = (float*)d_out;                     // scratch use of d_out (after oproj)

  k_agent<<<4*NTOK, 256, 0, stream>>>(fir, fvis, aw1, ab1, aw2, ab2, lf);
  k_select<<<4, 256, 0, stream>>>(lf, msk, sel);

  for (int mdl = 0; mdl < 2; ++mdl){
    const float* f = mdl ? fvis : fir;
    int p = 6 + mdl*10;
    const float* lng  = (const float*)d_in[p+0];
    const float* lnb  = (const float*)d_in[p+1];
    const float* wqkv = (const float*)d_in[p+2];
    const float* bqkv = (const float*)d_in[p+3];
    const float* wo   = (const float*)d_in[p+4];
    const float* bo   = (const float*)d_in[p+5];
    const float* w1   = (const float*)d_in[p+6];
    const float* b1   = (const float*)d_in[p+7];
    const float* w2   = (const float*)d_in[p+8];
    const float* b2   = (const float*)d_in[p+9];
    k_ln_qkv  <<<4*NTOK, 256, 0, stream>>>(f, lng, lnb, wqkv, bqkv, qkv);
    k_attn    <<<4*NH*(NTOK/64), 256, 0, stream>>>(qkv, sel, attno);
    k_oproj_ln<<<4*NTOK, 256, 0, stream>>>(attno, wo, bo, f, lng, lnb, x1, xn);
    k_gemm1   <<<144*16, 256, 0, stream>>>(xn, w1, b1, H);
    k_gemm2   <<<144*4, 256, 0, stream>>>(H, w2, b2, x1, mo, mdl);
  }

  k_combine<<<(4*CDIM*NTOK)/256, 256, 0, stream>>>(fir, fvis, sel, msk, mo, (float*)d_out);
}

// Round 13
// 4289.086 us; speedup vs baseline: 2.2441x; 1.2127x over previous
//
#include <hip/hip_runtime.h>
#include <hip/hip_bf16.h>
#include <math.h>

#define NTOK 2304
#define CDIM 256
#define NH 4
#define DHD 64

typedef __hip_bfloat16 bf16;

// block-wide sum over 256 threads; all threads receive the result
__device__ __forceinline__ float blk_sum256(float v, float* red){
  int t = threadIdx.x;
  red[t] = v; __syncthreads();
  #pragma unroll
  for (int s = 128; s > 0; s >>= 1){
    if (t < s) red[t] += red[t+s];
    __syncthreads();
  }
  float r = red[0]; __syncthreads();
  return r;
}

__device__ __forceinline__ void fma4(const float4 w, const float* x, int c, float& acc){
  acc += w.x*x[c] + w.y*x[c+1] + w.z*x[c+2] + w.w*x[c+3];
}

__device__ __forceinline__ float bfu(unsigned short s){
  union{unsigned u; float f;} a; a.u = ((unsigned)s)<<16; return a.f;
}

// ---------------- K0: sentinel fill (f32) ----------------
__global__ __launch_bounds__(256) void k_fill(float* __restrict__ out, int n, float v){
  int i = blockIdx.x*256 + threadIdx.x;
  if (i < n) out[i] = v;
}

// ---------------- K-XT: transpose [B,C,N] -> XT[pix][512] (fir | fvis) ----------------
__global__ __launch_bounds__(256) void k_xt(const float* __restrict__ fir, const float* __restrict__ fvis,
    float* __restrict__ XT)
{
  __shared__ float S[64*68];
  int tid = threadIdx.x;
  int bi = blockIdx.x;            // ((b*36)+nt)*8 + ct
  int ct = bi & 7;                // c-tile: 0..3 fir, 4..7 fvis
  int nt = (bi >> 3) % 36;
  int b  = bi / (36*8);
  const float* src = (ct < 4) ? fir : fvis;
  int c0 = (ct & 3) * 64;
  for (int c = tid; c < 1024; c += 256){
    int cr = c >> 4, n4 = c & 15;
    *(float4*)(S + cr*68 + n4*4) =
      *(const float4*)(src + (size_t)(b*CDIM + c0 + cr)*NTOK + nt*64 + n4*4);
  }
  __syncthreads();
  for (int c = tid; c < 1024; c += 256){
    int nr = c >> 4, c4 = c & 15;
    float4 v;
    v.x = S[(c4*4+0)*68 + nr];
    v.y = S[(c4*4+1)*68 + nr];
    v.z = S[(c4*4+2)*68 + nr];
    v.w = S[(c4*4+3)*68 + nr];
    *(float4*)(XT + (size_t)(b*NTOK + nt*64 + nr)*512 + ct*64 + c4*4) = v;
  }
}

// ---------------- K1: agent as GEMM + fused SiLU/aw2 reduce -> atomicAdd lf ----------------
__global__ __launch_bounds__(256) void k_agent_g(const float* __restrict__ XT,
    const float* __restrict__ aw1, const float* __restrict__ ab1,
    const float* __restrict__ aw2, float* __restrict__ lf)
{
  __shared__ float Xs[64*68];
  __shared__ float Ws[64*68];
  __shared__ float Rs[64*17];
  int tid = threadIdx.x;
  int bi = blockIdx.x;             // ((b*36)+nt)*8 + ot
  int ot = bi & 7;
  int nt = (bi >> 3) % 36;
  int b  = bi / (36*8);
  int pixbase = b*NTOK + nt*64;
  int o0 = ot*64;
  int pi = tid & 15, oj = tid >> 4;
  float acc[4][4] = {{0.f}};
  for (int k0 = 0; k0 < 512; k0 += 64){
    __syncthreads();
    for (int c = tid; c < 1024; c += 256){
      int r = c >> 4, f4 = c & 15;
      *(float4*)(Xs + r*68 + f4*4) = *(const float4*)(XT  + (size_t)(pixbase + r)*512 + k0 + f4*4);
      *(float4*)(Ws + r*68 + f4*4) = *(const float4*)(aw1 + (size_t)(o0 + r)*512 + k0 + f4*4);
    }
    __syncthreads();
    #pragma unroll 4
    for (int k4 = 0; k4 < 16; ++k4){
      float4 xv[4], wv[4];
      #pragma unroll
      for (int i = 0; i < 4; ++i) xv[i] = *(const float4*)(Xs + (pi+16*i)*68 + k4*4);
      #pragma unroll
      for (int j = 0; j < 4; ++j) wv[j] = *(const float4*)(Ws + (oj+16*j)*68 + k4*4);
      #pragma unroll
      for (int i = 0; i < 4; ++i){
        #pragma unroll
        for (int j = 0; j < 4; ++j){
          acc[i][j] += xv[i].x*wv[j].x + xv[i].y*wv[j].y + xv[i].z*wv[j].z + xv[i].w*wv[j].w;
        }
      }
    }
  }
  // fused epilogue: silu(acc + ab1) * aw2, partial-reduce over this block's 64 o's
  float part[4];
  #pragma unroll
  for (int i = 0; i < 4; ++i){
    float p = 0.f;
    #pragma unroll
    for (int j = 0; j < 4; ++j){
      int o = o0 + oj + 16*j;
      float v = acc[i][j] + ab1[o];
      float s = v / (1.f + expf(-v));
      p += s * aw2[o];
    }
    part[i] = p;
  }
  __syncthreads();
  #pragma unroll
  for (int i = 0; i < 4; ++i) Rs[(pi + 16*i)*17 + oj] = part[i];
  __syncthreads();
  if (tid < 64){
    float s = 0.f;
    #pragma unroll
    for (int j = 0; j < 16; ++j) s += Rs[tid*17 + j];
    atomicAdd(lf + pixbase + tid, s);
  }
}

// ---------------- K2: selection mask + top-64 fallback (OOB hardened) ----------------
__global__ __launch_bounds__(256) void k_select(const float* __restrict__ lf,
    const float* __restrict__ ab2,
    float* __restrict__ msk, int* __restrict__ sel)
{
  __shared__ float vals[NTOK];
  __shared__ int   ired[256];
  __shared__ float rmax[256];
  __shared__ int   rix[256];
  int b = blockIdx.x;
  int t = threadIdx.x;
  float ab2f = ab2[0];
  int cnt = 0;
  for (int n = t; n < NTOK; n += 256){
    float v = lf[b*NTOK + n] + ab2f;
    vals[n] = v;
    int m = (v > 0.f) ? 1 : 0;
    msk[b*NTOK + n] = (float)m;
    sel[b*NTOK + n] = m;
    cnt += m;
  }
  ired[t] = cnt; __syncthreads();
  #pragma unroll
  for (int s = 128; s > 0; s >>= 1){
    if (t < s) ired[t] += ired[t+s];
    __syncthreads();
  }
  int count = ired[0];
  __syncthreads();
  if (count < 64){
    for (int n = t; n < NTOK; n += 256) sel[b*NTOK + n] = 0;
    __syncthreads();
    for (int it = 0; it < 64; ++it){
      float bestv = -INFINITY; int besti = t;
      for (int n = t; n < NTOK; n += 256){
        float v = vals[n];
        if (v > bestv || (v == bestv && n < besti)){ bestv = v; besti = n; }
      }
      rmax[t] = bestv; rix[t] = besti; __syncthreads();
      #pragma unroll
      for (int s = 128; s > 0; s >>= 1){
        if (t < s){
          if (rmax[t+s] > rmax[t] || (rmax[t+s] == rmax[t] && rix[t+s] < rix[t])){
            rmax[t] = rmax[t+s]; rix[t] = rix[t+s];
          }
        }
        __syncthreads();
      }
      if (t == 0){
        int w = rix[0];
        if (w >= 0 && w < NTOK){ sel[b*NTOK + w] = 1; vals[w] = -INFINITY; }
      }
      __syncthreads();
    }
  }
}

// ---------------- K3: LN + QKV projection ----------------
__global__ __launch_bounds__(256) void k_ln_qkv(const float* __restrict__ f,
    const float* __restrict__ lng, const float* __restrict__ lnb,
    const float* __restrict__ wqkv, const float* __restrict__ bqkv,
    float* __restrict__ qkv)
{
  __shared__ float xn[256];
  __shared__ float red[256];
  int t = threadIdx.x;
  int pix = blockIdx.x;
  int b = pix / NTOK, n = pix % NTOK;
  float x = f[(size_t)(b*CDIM + t)*NTOK + n];
  float m  = blk_sum256(x,   red) * (1.f/256.f);
  float sq = blk_sum256(x*x, red) * (1.f/256.f);
  float rstd = rsqrtf(sq - m*m + 1e-5f);
  xn[t] = (x - m)*rstd*lng[t] + lnb[t];
  __syncthreads();
  size_t obase = (size_t)pix * 768;
  #pragma unroll
  for (int oi = 0; oi < 3; ++oi){
    int o = t + oi*256;
    const float4* w4 = reinterpret_cast<const float4*>(wqkv + (size_t)o*256);
    float acc = bqkv[o];
    #pragma unroll 8
    for (int c4 = 0; c4 < 64; ++c4){
      fma4(w4[c4], xn, c4*4, acc);
    }
    qkv[obase + o] = acc;
  }
}

// ---------------- K4: masked attention, register-tiled 4x4, float4 LDS ----------------
__global__ __launch_bounds__(256) void k_attn(const float* __restrict__ qkv,
    const int* __restrict__ sel, float* __restrict__ attno)
{
  __shared__ float Qs[64*68];
  __shared__ float Ks[64*68];
  __shared__ float Vs[64*68];
  __shared__ float Ps[64*68];
  __shared__ int selk[64];
  int tid = threadIdx.x;
  int w  = tid >> 6;
  int l  = tid & 63;
  int kg = l & 15;
  int qh = l >> 4;
  int qbase = w*16 + qh;     // + 4*i
  int bi = blockIdx.x;
  int qt = bi % 36; int h = (bi/36) % NH; int b = bi / (36*NH);

  for (int c = tid; c < 1024; c += 256){
    int r = c >> 4, d4 = c & 15;
    float4 v = *(const float4*)(qkv + (size_t)(b*NTOK + qt*64 + r)*768 + h*64 + d4*4);
    *(float4*)(Qs + r*68 + d4*4) = v;
  }

  float m_[4], l_[4], o_[4][4];
  #pragma unroll
  for (int i = 0; i < 4; ++i){
    m_[i] = -INFINITY; l_[i] = 0.f;
    o_[i][0]=0.f; o_[i][1]=0.f; o_[i][2]=0.f; o_[i][3]=0.f;
  }

  for (int kt = 0; kt < 36; ++kt){
    __syncthreads();
    for (int c = tid; c < 1024; c += 256){
      int r = c >> 4, d4 = c & 15;
      size_t base = (size_t)(b*NTOK + kt*64 + r)*768 + h*64 + d4*4;
      *(float4*)(Ks + r*68 + d4*4) = *(const float4*)(qkv + base + 256);
      *(float4*)(Vs + r*68 + d4*4) = *(const float4*)(qkv + base + 512);
    }
    if (tid < 64) selk[tid] = sel[b*NTOK + kt*64 + tid];
    __syncthreads();

    float s[4][4];
    #pragma unroll
    for (int i = 0; i < 4; ++i){ s[i][0]=0.f; s[i][1]=0.f; s[i][2]=0.f; s[i][3]=0.f; }
    #pragma unroll 4
    for (int d4 = 0; d4 < 16; ++d4){
      float4 qv[4], kv[4];
      #pragma unroll
      for (int i = 0; i < 4; ++i) qv[i] = *(const float4*)(Qs + (qbase+4*i)*68 + d4*4);
      #pragma unroll
      for (int j = 0; j < 4; ++j) kv[j] = *(const float4*)(Ks + (kg+16*j)*68 + d4*4);
      #pragma unroll
      for (int i = 0; i < 4; ++i){
        #pragma unroll
        for (int j = 0; j < 4; ++j){
          s[i][j] += qv[i].x*kv[j].x + qv[i].y*kv[j].y + qv[i].z*kv[j].z + qv[i].w*kv[j].w;
        }
      }
    }
    int ms0 = selk[kg], ms1 = selk[kg+16], ms2 = selk[kg+32], ms3 = selk[kg+48];
    #pragma unroll
    for (int i = 0; i < 4; ++i){
      s[i][0] = ms0 ? s[i][0]*0.125f : -1e9f;
      s[i][1] = ms1 ? s[i][1]*0.125f : -1e9f;
      s[i][2] = ms2 ? s[i][2]*0.125f : -1e9f;
      s[i][3] = ms3 ? s[i][3]*0.125f : -1e9f;
    }
    float p[4][4];
    #pragma unroll
    for (int i = 0; i < 4; ++i){
      float mx = fmaxf(fmaxf(s[i][0], s[i][1]), fmaxf(s[i][2], s[i][3]));
      #pragma unroll
      for (int off = 8; off; off >>= 1) mx = fmaxf(mx, __shfl_xor(mx, off, 16));
      float mnew = fmaxf(m_[i], mx);
      float fs = expf(m_[i] - mnew);
      p[i][0] = expf(s[i][0] - mnew); p[i][1] = expf(s[i][1] - mnew);
      p[i][2] = expf(s[i][2] - mnew); p[i][3] = expf(s[i][3] - mnew);
      float ps = p[i][0] + p[i][1] + p[i][2] + p[i][3];
      #pragma unroll
      for (int off = 8; off; off >>= 1) ps += __shfl_xor(ps, off, 16);
      l_[i] = l_[i]*fs + ps; m_[i] = mnew;
      o_[i][0]*=fs; o_[i][1]*=fs; o_[i][2]*=fs; o_[i][3]*=fs;
    }
    #pragma unroll
    for (int i = 0; i < 4; ++i){
      Ps[(qbase+4*i)*68 + kg     ] = p[i][0];
      Ps[(qbase+4*i)*68 + kg + 16] = p[i][1];
      Ps[(qbase+4*i)*68 + kg + 32] = p[i][2];
      Ps[(qbase+4*i)*68 + kg + 48] = p[i][3];
    }
    #pragma unroll 4
    for (int k4 = 0; k4 < 16; ++k4){
      float4 pv[4], vv[4];
      #pragma unroll
      for (int i = 0; i < 4; ++i) pv[i] = *(const float4*)(Ps + (qbase+4*i)*68 + k4*4);
      #pragma unroll
      for (int jj = 0; jj < 4; ++jj) vv[jj] = *(const float4*)(Vs + (k4*4+jj)*68 + kg*4);
      #pragma unroll
      for (int i = 0; i < 4; ++i){
        o_[i][0] += pv[i].x*vv[0].x + pv[i].y*vv[1].x + pv[i].z*vv[2].x + pv[i].w*vv[3].x;
        o_[i][1] += pv[i].x*vv[0].y + pv[i].y*vv[1].y + pv[i].z*vv[2].y + pv[i].w*vv[3].y;
        o_[i][2] += pv[i].x*vv[0].z + pv[i].y*vv[1].z + pv[i].z*vv[2].z + pv[i].w*vv[3].z;
        o_[i][3] += pv[i].x*vv[0].w + pv[i].y*vv[1].w + pv[i].z*vv[2].w + pv[i].w*vv[3].w;
      }
    }
  }
  #pragma unroll
  for (int i = 0; i < 4; ++i){
    float inv = 1.f / l_[i];
    int row = qt*64 + qbase + 4*i;
    float4 ov; ov.x = o_[i][0]*inv; ov.y = o_[i][1]*inv; ov.z = o_[i][2]*inv; ov.w = o_[i][3]*inv;
    *(float4*)(attno + (size_t)(b*NTOK + row)*256 + h*64 + kg*4) = ov;
  }
}

// ---------------- K5: O-projection + residual + fused LN (xn for FFN) ----------------
__global__ __launch_bounds__(256) void k_oproj_ln(const float* __restrict__ attno,
    const float* __restrict__ wo, const float* __restrict__ bo,
    const float* __restrict__ f,
    const float* __restrict__ lng, const float* __restrict__ lnb,
    float* __restrict__ x1, float* __restrict__ xn_out)
{
  __shared__ float orow[256];
  __shared__ float red[256];
  int t = threadIdx.x;
  int pix = blockIdx.x;
  int b = pix / NTOK, n = pix % NTOK;
  orow[t] = attno[(size_t)pix*256 + t];
  __syncthreads();
  const float4* w4 = reinterpret_cast<const float4*>(wo + (size_t)t*256);
  float acc = bo[t];
  #pragma unroll 8
  for (int c4 = 0; c4 < 64; ++c4){
    fma4(w4[c4], orow, c4*4, acc);
  }
  float v = acc + f[(size_t)(b*CDIM + t)*NTOK + n];
  x1[(size_t)pix*256 + t] = v;
  float m  = blk_sum256(v,   red) * (1.f/256.f);
  float sq = blk_sum256(v*v, red) * (1.f/256.f);
  float rstd = rsqrtf(sq - m*m + 1e-5f);
  xn_out[(size_t)pix*256 + t] = (v - m)*rstd*lng[t] + lnb[t];
}

// ---------------- K6a: GEMM1 H = gelu(xn . W1^T + b1), bf16 out ----------------
__global__ __launch_bounds__(256) void k_gemm1(const float* __restrict__ xn,
    const float* __restrict__ w1, const float* __restrict__ b1,
    bf16* __restrict__ H)
{
  __shared__ float Xs[64*68];
  __shared__ float Ws[64*68];
  int tid = threadIdx.x;
  int bp = blockIdx.x % 144, bh = blockIdx.x / 144;
  int pi = tid & 15, hj = tid >> 4;
  float acc[4][4] = {{0.f}};
  for (int k0 = 0; k0 < 256; k0 += 64){
    __syncthreads();
    for (int c = tid; c < 1024; c += 256){
      int r = c >> 4, f4 = c & 15;
      *(float4*)(Xs + r*68 + f4*4) = *(const float4*)(xn + (size_t)(bp*64 + r)*256 + k0 + f4*4);
      *(float4*)(Ws + r*68 + f4*4) = *(const float4*)(w1 + (size_t)(bh*64 + r)*256 + k0 + f4*4);
    }
    __syncthreads();
    #pragma unroll 4
    for (int k4 = 0; k4 < 16; ++k4){
      float4 xv[4], wv[4];
      #pragma unroll
      for (int i = 0; i < 4; ++i) xv[i] = *(const float4*)(Xs + (pi+16*i)*68 + k4*4);
      #pragma unroll
      for (int j = 0; j < 4; ++j) wv[j] = *(const float4*)(Ws + (hj+16*j)*68 + k4*4);
      #pragma unroll
      for (int i = 0; i < 4; ++i){
        #pragma unroll
        for (int j = 0; j < 4; ++j){
          acc[i][j] += xv[i].x*wv[j].x + xv[i].y*wv[j].y + xv[i].z*wv[j].z + xv[i].w*wv[j].w;
        }
      }
    }
  }
  #pragma unroll
  for (int i = 0; i < 4; ++i){
    int p = bp*64 + pi + 16*i;
    #pragma unroll
    for (int j = 0; j < 4; ++j){
      int hh = bh*64 + hj + 16*j;
      float v = acc[i][j] + b1[hh];
      v = 0.5f*v*(1.f + erff(v*0.70710678118654752f));
      H[(size_t)p*1024 + hh] = __float2bfloat16(v);
    }
  }
}

// ---------------- K6b: GEMM2 mo (+)= x1 + H . W2^T + b2 ----------------
__global__ __launch_bounds__(256) void k_gemm2(const bf16* __restrict__ H,
    const float* __restrict__ w2, const float* __restrict__ b2,
    const float* __restrict__ x1, float* __restrict__ mo, int accum)
{
  __shared__ float Hs[64*68];
  __shared__ float Ws[64*68];
  int tid = threadIdx.x;
  int bp = blockIdx.x % 144, bo = blockIdx.x / 144;  // bo in 0..3
  int pi = tid & 15, oj = tid >> 4;
  float acc[4][4] = {{0.f}};
  for (int k0 = 0; k0 < 1024; k0 += 64){
    __syncthreads();
    for (int c = tid; c < 1024; c += 256){
      int r = c >> 4, f4 = c & 15;
      const ushort4 u = *(const ushort4*)(H + (size_t)(bp*64 + r)*1024 + k0 + f4*4);
      float4 hv; hv.x = bfu(u.x); hv.y = bfu(u.y); hv.z = bfu(u.z); hv.w = bfu(u.w);
      *(float4*)(Hs + r*68 + f4*4) = hv;
      *(float4*)(Ws + r*68 + f4*4) = *(const float4*)(w2 + (size_t)(bo*64 + r)*1024 + k0 + f4*4);
    }
    __syncthreads();
    #pragma unroll 4
    for (int k4 = 0; k4 < 16; ++k4){
      float4 hv[4], wv[4];
      #pragma unroll
      for (int i = 0; i < 4; ++i) hv[i] = *(const float4*)(Hs + (pi+16*i)*68 + k4*4);
      #pragma unroll
      for (int j = 0; j < 4; ++j) wv[j] = *(const float4*)(Ws + (oj+16*j)*68 + k4*4);
      #pragma unroll
      for (int i = 0; i < 4; ++i){
        #pragma unroll
        for (int j = 0; j < 4; ++j){
          acc[i][j] += hv[i].x*wv[j].x + hv[i].y*wv[j].y + hv[i].z*wv[j].z + hv[i].w*wv[j].w;
        }
      }
    }
  }
  #pragma unroll
  for (int i = 0; i < 4; ++i){
    int p = bp*64 + pi + 16*i;
    #pragma unroll
    for (int j = 0; j < 4; ++j){
      int o = bo*64 + oj + 16*j;
      size_t idx = (size_t)p*256 + o;
      float v = acc[i][j] + b2[o] + x1[idx];
      mo[idx] = accum ? (mo[idx] + v) : v;
    }
  }
}

// ---------------- K7: scatter-combine into canvas (f32 out) ----------------
__global__ __launch_bounds__(256) void k_combine(const float* __restrict__ fir, const float* __restrict__ fvis,
    const int* __restrict__ sel, const float* __restrict__ msk,
    const float* __restrict__ mo, float* __restrict__ out)
{
  size_t i = (size_t)blockIdx.x*256 + threadIdx.x;
  int n = (int)(i % NTOK);
  size_t bc = i / NTOK;
  int cc = (int)(bc % CDIM);
  int b  = (int)(bc / CDIM);
  float base = fir[i] + fvis[i];
  int bn = b*NTOK + n;
  float r;
  if (sel[bn]){
    r = mo[(size_t)bn*256 + cc] * msk[bn];
  } else {
    r = base;
  }
  out[i] = r;
}

extern "C" void kernel_launch(void* const* d_in, const int* in_sizes, int n_in,
                              void* d_out, int out_size, void* d_ws, size_t ws_size,
                              hipStream_t stream)
{
  static const int expected[26] = {
    2359296, 2359296, 262144, 512, 512, 1,
    256, 256, 196608, 768, 65536, 256, 262144, 1024, 262144, 256,
    256, 256, 196608, 768, 65536, 256, 262144, 1024, 262144, 256
  };
  const size_t WS_NEEDED = 37859328;
  float sentinel = 0.f; bool fail = false;
  if (n_in != 26){ sentinel = 1e9f; fail = true; }
  else {
    for (int i = 0; i < 26; ++i){
      if (in_sizes[i] != expected[i]){ sentinel = 1e6f * (float)(i+1); fail = true; break; }
    }
    if (!fail && ws_size < WS_NEEDED){ sentinel = 100.f + (float)(ws_size >> 10); fail = true; }
  }
  if (fail){
    k_fill<<<(out_size + 255)/256, 256, 0, stream>>>((float*)d_out, out_size, sentinel);
    return;
  }

  const float* fir  = (const float*)d_in[0];
  const float* fvis = (const float*)d_in[1];
  const float* aw1  = (const float*)d_in[2];
  const float* ab1  = (const float*)d_in[3];
  const float* aw2  = (const float*)d_in[4];
  const float* ab2  = (const float*)d_in[5];

  // Workspace layout (37.86 MB, unchanged):
  //   [0)         lf   f32 x 9216  (zero-filled; agent GEMM atomicAdds partials)
  //   [36864)     msk  f32 x 9216
  //   [73728)     sel  i32 x 9216
  //   [110592)    mo   f32 x 2359296   (ir writes; vis accumulates -> ri+rv)
  //   [9547776)   28.3MB region, multiplexed in time:
  //      XT (f32 x 9216x512, 18.9MB)   = agent phase (dead after k_agent_g)
  //      qkv (f32 x 7077888, 27MB)     = per-modality (dead after k_attn)
  //      x1 (f32 x 2359296, 9.4MB)     = first part, after attn
  //      H  (bf16 x 9216x1024, 18.9MB) = tail, during gemm1/gemm2
  // attno AND xn live in d_out (dead before combine overwrites).
  char* wsb = (char*)d_ws;
  float* lf    = (float*)(wsb + 0);
  float* msk   = (float*)(wsb + 36864);
  int*   sel   = (int*)  (wsb + 73728);
  float* mo    = (float*)(wsb + 110592);
  float* XT    = (float*)(wsb + 9547776);
  float* qkv   = (float*)(wsb + 9547776);
  float* x1    = (float*)(wsb + 9547776);
  bf16*  H     = (bf16*) (wsb + 9547776 + 9437184);
  float* attno = (float*)d_out;
  float* xn    = (float*)d_out;

  k_fill   <<<36, 256, 0, stream>>>(lf, 9216, 0.f);
  k_xt     <<<1152, 256, 0, stream>>>(fir, fvis, XT);
  k_agent_g<<<1152, 256, 0, stream>>>(XT, aw1, ab1, aw2, lf);
  k_select <<<4, 256, 0, stream>>>(lf, ab2, msk, sel);

  for (int mdl = 0; mdl < 2; ++mdl){
    const float* f = mdl ? fvis : fir;
    int p = 6 + mdl*10;
    const float* lng  = (const float*)d_in[p+0];
    const float* lnb  = (const float*)d_in[p+1];
    const float* wqkv = (const float*)d_in[p+2];
    const float* bqkv = (const float*)d_in[p+3];
    const float* wo   = (const float*)d_in[p+4];
    const float* bo   = (const float*)d_in[p+5];
    const float* w1   = (const float*)d_in[p+6];
    const float* b1   = (const float*)d_in[p+7];
    const float* w2   = (const float*)d_in[p+8];
    const float* b2   = (const float*)d_in[p+9];
    k_ln_qkv  <<<4*NTOK, 256, 0, stream>>>(f, lng, lnb, wqkv, bqkv, qkv);
    k_attn    <<<4*NH*(NTOK/64), 256, 0, stream>>>(qkv, sel, attno);
    k_oproj_ln<<<4*NTOK, 256, 0, stream>>>(attno, wo, bo, f, lng, lnb, x1, xn);
    k_gemm1   <<<144*16, 256, 0, stream>>>(xn, w1, b1, H);
    k_gemm2   <<<144*4, 256, 0, stream>>>(H, w2, b2, x1, mo, mdl);
  }

  k_combine<<<(4*CDIM*NTOK)/256, 256, 0, stream>>>(fir, fvis, sel, msk, mo, (float*)d_out);
}